// Round 8
// baseline (1511.354 us; speedup 1.0000x reference)
//
#include <hip/hip_runtime.h>
#include <math.h>

// ---- problem dims ----
#define NB 2
#define NSEQ 4096
#define DMODEL 384
#define NH 8
#define DKQ 48
#define DV 48
#define TOPK 128
#define NQ (NB*NSEQ)          // 8192 total query rows

// fp32 combined projection: [q(384) | k(48) | v(48)] = 480 cols
#define QKV_COLS 480
#define C_Q 0
#define C_K 384
#define C_V 432
// fp64 indexer projection Pd[8192][128]: [qi0(32)|qi1(32)|ki(32)|w(2)|pad]
#define IDX_COLS 128
#define P_QI 0
#define P_KI 64
#define P_W  96
#define ATT_SCALE 0.14433756729740643f   // 48^-0.5

typedef double v4d  __attribute__((ext_vector_type(4)));
typedef float  f32x4 __attribute__((ext_vector_type(4)));
typedef short  s16x8 __attribute__((ext_vector_type(8)));

// round-to-nearest-even bf16 split: v ~= hi + lo
__device__ inline void bsplit(float v, unsigned short& h, unsigned short& l) {
    unsigned hb = __float_as_uint(v);
    unsigned short hi = (unsigned short)((hb + 0x7FFFu + ((hb >> 16) & 1u)) >> 16);
    float hf = __uint_as_float(((unsigned)hi) << 16);
    float r = v - hf;
    unsigned rb = __float_as_uint(r);
    unsigned short lo = (unsigned short)((rb + 0x7FFFu + ((rb >> 16) & 1u)) >> 16);
    h = hi; l = lo;
}

// ------------------------------------------------------------------
// split x into bf16 hi/lo
// ------------------------------------------------------------------
__global__ void k_split(const float* __restrict__ x,
                        unsigned short* __restrict__ xhi, unsigned short* __restrict__ xlo) {
    int i = blockIdx.x * 256 + threadIdx.x;
    if (i < NQ * DMODEL) {
        unsigned short h, l;
        bsplit(x[i], h, l);
        xhi[i] = h; xlo[i] = l;
    }
}

// ------------------------------------------------------------------
// concat + transpose + split weights
// ------------------------------------------------------------------
__global__ void k_concat(const float* __restrict__ wq_idx, const float* __restrict__ wk_idx,
                         const float* __restrict__ ww_idx, const float* __restrict__ wq,
                         const float* __restrict__ wk, const float* __restrict__ wv,
                         const float* __restrict__ wo,
                         unsigned short* __restrict__ WqT_hi, unsigned short* __restrict__ WqT_lo,
                         unsigned short* __restrict__ WoT_hi, unsigned short* __restrict__ WoT_lo,
                         float* __restrict__ Wi_cat) {
    int i = blockIdx.x * 256 + threadIdx.x;
    const int NQK = QKV_COLS * DMODEL;          // 184320
    const int NWO = DMODEL * DMODEL;            // 147456
    if (i < NQK) {
        int n = i / DMODEL, k = i % DMODEL;
        float v;
        if (n < 384)      v = wq[(size_t)k*384 + n];
        else if (n < 432) v = wk[(size_t)k*48 + (n-384)];
        else              v = wv[(size_t)k*48 + (n-432)];
        unsigned short h, l; bsplit(v, h, l);
        WqT_hi[i] = h; WqT_lo[i] = l;
    } else if (i < NQK + NWO) {
        int j = i - NQK;
        int n = j / DMODEL, k = j % DMODEL;
        float v = wo[(size_t)k*384 + n];
        unsigned short h, l; bsplit(v, h, l);
        WoT_hi[j] = h; WoT_lo[j] = l;
    } else if (i < NQK + NWO + DMODEL*IDX_COLS) {
        int j = i - NQK - NWO;
        int d = j / IDX_COLS, c = j % IDX_COLS;
        float v;
        if (c < 64)       v = wq_idx[d*64 + c];
        else if (c < 96)  v = wk_idx[d*32 + (c-64)];
        else if (c < 98)  v = ww_idx[d*2 + (c-96)];
        else              v = 0.f;
        Wi_cat[j] = v;
    }
}

// ------------------------------------------------------------------
// split-bf16 MFMA GEMM: C[M x N] = (Ahi+Alo)[M x 384] @ (Bhi+Blo)^T
// ------------------------------------------------------------------
#define GLDK 40   // shorts per LDS row (32 + 8 pad)
__global__ __launch_bounds__(256) void k_gemm_mfma(
        const unsigned short* __restrict__ Ahi, const unsigned short* __restrict__ Alo,
        const unsigned short* __restrict__ Bhi, const unsigned short* __restrict__ Blo,
        float* __restrict__ C, int N, int ldc) {
    __shared__ unsigned short At[2][128][GLDK];
    __shared__ unsigned short Bt[2][64][GLDK];
    const int t = threadIdx.x;
    const int lane = t & 63, wid = t >> 6;
    const int row0 = blockIdx.y * 128, col0 = blockIdx.x * 64;
    const int ml = lane & 15, kq = lane >> 4;
    const int wm = (wid & 1) * 64, wn = (wid >> 1) * 32;

    // ---- layout calibration probes ----
    unsigned short mv = (unsigned short)(__float_as_uint((float)(ml + 1)) >> 16);
    unsigned short one = 0x3F80;
    s16x8 pa, pb;
    #pragma unroll
    for (int j = 0; j < 8; j++) { pa[j] = (short)mv; pb[j] = (short)one; }
    f32x4 zf = (f32x4){0.f, 0.f, 0.f, 0.f};
    f32x4 rowp = __builtin_amdgcn_mfma_f32_16x16x32_bf16(pa, pb, zf, 0, 0, 0);
    f32x4 colp = __builtin_amdgcn_mfma_f32_16x16x32_bf16(pb, pa, zf, 0, 0, 0);
    int rowm[4], colm[4];
    #pragma unroll
    for (int r = 0; r < 4; r++) {
        rowm[r] = (((int)(rowp[r] * 0.03125f + 0.5f)) - 1) & 15;
        colm[r] = (((int)(colp[r] * 0.03125f + 0.5f)) - 1) & 15;
    }

    f32x4 acc[4][2];
    #pragma unroll
    for (int mt = 0; mt < 4; mt++)
        #pragma unroll
        for (int nt = 0; nt < 2; nt++) acc[mt][nt] = zf;

    for (int k0 = 0; k0 < DMODEL; k0 += 32) {
        #pragma unroll
        for (int i = 0; i < 4; i++) {
            int ch = t + 256*i;
            int arr = ch >> 9, rem = ch & 511;
            int r = rem >> 2, p = rem & 3;
            const unsigned short* src = arr ? Alo : Ahi;
            *(int4*)&At[arr][r][p*8] = *(const int4*)(src + (size_t)(row0 + r)*DMODEL + k0 + p*8);
        }
        #pragma unroll
        for (int i = 0; i < 2; i++) {
            int ch = t + 256*i;
            int arr = ch >> 8, rem = ch & 255;
            int r = rem >> 2, p = rem & 3;
            const unsigned short* src = arr ? Blo : Bhi;
            int gc = col0 + r;
            int4 v = {0, 0, 0, 0};
            if (gc < N) v = *(const int4*)(src + (size_t)gc*DMODEL + k0 + p*8);
            *(int4*)&Bt[arr][r][p*8] = v;
        }
        __syncthreads();
        s16x8 af[4][2], bfr[2][2];
        #pragma unroll
        for (int mt = 0; mt < 4; mt++)
            #pragma unroll
            for (int h = 0; h < 2; h++)
                af[mt][h] = *(const s16x8*)&At[h][wm + mt*16 + ml][kq*8];
        #pragma unroll
        for (int nt = 0; nt < 2; nt++)
            #pragma unroll
            for (int h = 0; h < 2; h++)
                bfr[nt][h] = *(const s16x8*)&Bt[h][wn + nt*16 + ml][kq*8];
        #pragma unroll
        for (int mt = 0; mt < 4; mt++)
            #pragma unroll
            for (int nt = 0; nt < 2; nt++) {
                acc[mt][nt] = __builtin_amdgcn_mfma_f32_16x16x32_bf16(af[mt][0], bfr[nt][0], acc[mt][nt], 0, 0, 0);
                acc[mt][nt] = __builtin_amdgcn_mfma_f32_16x16x32_bf16(af[mt][0], bfr[nt][1], acc[mt][nt], 0, 0, 0);
                acc[mt][nt] = __builtin_amdgcn_mfma_f32_16x16x32_bf16(af[mt][1], bfr[nt][0], acc[mt][nt], 0, 0, 0);
            }
        __syncthreads();
    }
    #pragma unroll
    for (int mt = 0; mt < 4; mt++)
        #pragma unroll
        for (int nt = 0; nt < 2; nt++)
            #pragma unroll
            for (int r = 0; r < 4; r++) {
                int rr = row0 + wm + mt*16 + rowm[r];
                int cc = col0 + wn + nt*16 + colm[r];
                if (cc < N) C[(size_t)rr*ldc + cc] = acc[mt][nt][r];
            }
}

// ------------------------------------------------------------------
// fp64-accumulated indexer projection: Pd[8192][128] = x @ Wi_cat
// ------------------------------------------------------------------
__global__ __launch_bounds__(256) void k_proj64(const float* __restrict__ A,
                                                const float* __restrict__ W,
                                                double* __restrict__ P) {
    __shared__ float At[16][32];
    __shared__ float Bt[16][IDX_COLS];
    const int t  = threadIdx.x;
    const int tx = t & 15;
    const int ty = t >> 4;
    const int row0 = blockIdx.x * 32;
    double acc[2][8] = {};

    for (int k0 = 0; k0 < DMODEL; k0 += 16) {
        if (t < 128) {
            int m = t >> 2, kc = t & 3;
            float4 a = *(const float4*)(A + (size_t)(row0 + m)*DMODEL + k0 + kc*4);
            At[kc*4+0][m] = a.x; At[kc*4+1][m] = a.y;
            At[kc*4+2][m] = a.z; At[kc*4+3][m] = a.w;
        }
        for (int i = 0; i < 2; i++) {
            int lin = t + i*256;
            int kk = lin >> 5, c4 = lin & 31;
            float4 b = *(const float4*)(W + (size_t)(k0+kk)*IDX_COLS + c4*4);
            *(float4*)&Bt[kk][c4*4] = b;
        }
        __syncthreads();
        for (int kk = 0; kk < 16; kk++) {
            float a2[2], b8[8];
            a2[0] = At[kk][ty*2]; a2[1] = At[kk][ty*2+1];
            *(float4*)&b8[0] = *(const float4*)&Bt[kk][tx*8];
            *(float4*)&b8[4] = *(const float4*)&Bt[kk][tx*8+4];
            for (int i = 0; i < 2; i++)
                for (int j = 0; j < 8; j++)
                    acc[i][j] += (double)a2[i] * (double)b8[j];
        }
        __syncthreads();
    }
    for (int i = 0; i < 2; i++)
        for (int j = 0; j < 8; j++)
            P[(size_t)(row0 + ty*2 + i)*IDX_COLS + tx*8 + j] = acc[i][j];
}

// ------------------------------------------------------------------
// fp64 index scores via MFMA f64 16x16x4, self-calibrated C/D layout.
// Also emits K32 = bias-flipped hi32 sortable key per score.
// ------------------------------------------------------------------
__global__ __launch_bounds__(256) void k_score_mfma(const double* __restrict__ P,
                                                    double* __restrict__ S,
                                                    unsigned int* __restrict__ K32,
                                                    int qstart) {
    __shared__ double A0[32][33];
    __shared__ double A1[32][33];
    __shared__ double Bk[32][129];
    __shared__ double wsh[2][32];
    const int t = threadIdx.x;
    const int lane = t & 63;
    const int wid = t >> 6;
    const int g0 = qstart + blockIdx.y * 32;
    const int b  = g0 / NSEQ;
    const int s0 = blockIdx.x * 128;

    for (int i = 0; i < 8; i++) {
        int lin = t + i*256;
        int q = lin >> 6, c = lin & 63;
        double v = P[(size_t)(g0 + q)*IDX_COLS + P_QI + c];
        if (c < 32) A0[c][q] = v; else A1[c-32][q] = v;
    }
    for (int i = 0; i < 16; i++) {
        int lin = t + i*256;
        int s = lin >> 5, c = lin & 31;
        Bk[c][s] = P[(size_t)(b*NSEQ + s0 + s)*IDX_COLS + P_KI + c];
    }
    if (t < 64) wsh[t & 1][t >> 1] = P[(size_t)(g0 + (t >> 1))*IDX_COLS + P_W + (t & 1)];

    const int qw = (wid & 1) * 16;
    const int sw = (wid >> 1) * 64;
    const int ml = lane & 15;
    const int kl = lane >> 4;

    v4d zero = (v4d){0.0, 0.0, 0.0, 0.0};
    v4d rowp = __builtin_amdgcn_mfma_f64_16x16x4f64((double)(ml+1), 1.0, zero, 0, 0, 0);
    v4d colp = __builtin_amdgcn_mfma_f64_16x16x4f64(1.0, (double)(ml+1), zero, 0, 0, 0);
    int rowm[4], colm[4];
    #pragma unroll
    for (int r = 0; r < 4; r++) {
        rowm[r] = (((int)(rowp[r] * 0.25 + 0.5)) - 1) & 15;
        colm[r] = (((int)(colp[r] * 0.25 + 0.5)) - 1) & 15;
    }

    __syncthreads();

    v4d acc0[4], acc1[4];
    #pragma unroll
    for (int st = 0; st < 4; st++) { acc0[st] = zero; acc1[st] = zero; }

    #pragma unroll
    for (int k4 = 0; k4 < 8; k4++) {
        int k = k4*4 + kl;
        double a0 = A0[k][qw + ml];
        double a1 = A1[k][qw + ml];
        #pragma unroll
        for (int st = 0; st < 4; st++) {
            double bb = Bk[k][sw + st*16 + ml];
            acc0[st] = __builtin_amdgcn_mfma_f64_16x16x4f64(a0, bb, acc0[st], 0, 0, 0);
            acc1[st] = __builtin_amdgcn_mfma_f64_16x16x4f64(a1, bb, acc1[st], 0, 0, 0);
        }
    }

    #pragma unroll
    for (int reg = 0; reg < 4; reg++) {
        int q = qw + rowm[reg];
        double w0 = wsh[0][q], w1 = wsh[1][q];
        #pragma unroll
        for (int st = 0; st < 4; st++) {
            double sc = w0 * fmax(acc0[st][reg], 0.0) + w1 * fmax(acc1[st][reg], 0.0);
            size_t oidx = (size_t)(blockIdx.y*32 + q)*NSEQ + s0 + sw + st*16 + colm[reg];
            S[oidx] = sc;
            unsigned long long bb = (unsigned long long)__double_as_longlong(sc);
            unsigned int h = (unsigned int)(bb >> 32);
            K32[oidx] = (h & 0x80000000u) ? ~h : (h | 0x80000000u);
        }
    }
}

// ------------------------------------------------------------------
// Wave-per-query top-128: register-resident hi32 radix select with
// ballot-ordered collection (no barriers, no collection atomics).
// Ties at threshold -> lowest index (jax.lax.top_k semantics).
// ------------------------------------------------------------------
__global__ __launch_bounds__(256, 4) void k_topk_wave(const unsigned int* __restrict__ K32,
                                                      const double* __restrict__ S,
                                                      int* __restrict__ IDX, int qstart) {
    __shared__ unsigned int hist[4][256];
    const int t = threadIdx.x, lane = t & 63, w = t >> 6;
    const int q = blockIdx.x * 4 + w;
    const unsigned int* krow = K32 + (size_t)q * NSEQ;
    int* orow = IDX + (size_t)(qstart + q) * TOPK;
    const unsigned long long lml = (1ULL << lane) - 1ULL;

    unsigned int keys[64];
    #pragma unroll
    for (int j = 0; j < 64; j++) keys[j] = krow[lane + 64*j];

    unsigned int need = TOPK, prefix = 0;
    int plen = 0;
    bool flag = false;

    #pragma unroll 1
    for (int p = 0; p < 4; p++) {
        *(uint4*)&hist[w][lane*4] = make_uint4(0, 0, 0, 0);
        const int sh = 24 - 8*p;
        #pragma unroll
        for (int j = 0; j < 64; j++) {
            bool act = (((unsigned long long)keys[j]) >> (sh + 8)) == (unsigned long long)prefix;
            unsigned long long bal = __ballot(act);
            if (bal) {
                unsigned int d = (keys[j] >> sh) & 255u;
                int src = __ffsll(bal) - 1;
                unsigned int d0 = __shfl(d, src, 64);
                bool uni = (__ballot(act && d == d0) == bal);
                if (uni) { if (lane == src) atomicAdd(&hist[w][d0], (unsigned int)__popcll(bal)); }
                else if (act) atomicAdd(&hist[w][d], 1u);
            }
        }
        // wave-local decide: suffix-scan 256 bins via shuffles
        uint4 c = *(uint4*)&hist[w][lane*4];
        unsigned int run = c.x + c.y + c.z + c.w;
        #pragma unroll
        for (int d2 = 1; d2 < 64; d2 <<= 1) {
            unsigned int v = __shfl_down(run, d2, 64);
            if (lane + d2 < 64) run += v;
        }
        unsigned int Ss[5];
        Ss[0] = run; Ss[1] = run - c.x; Ss[2] = Ss[1] - c.y; Ss[3] = Ss[2] - c.z; Ss[4] = Ss[3] - c.w;
        unsigned int enc = 0;
        #pragma unroll
        for (int jj = 0; jj < 4; jj++) {
            if (Ss[jj] >= need && Ss[jj+1] < need) {
                unsigned int nn = need - Ss[jj+1];
                unsigned int bc = Ss[jj] - Ss[jj+1];
                enc = 0x80000000u | ((unsigned int)(lane*4 + jj) << 16) | (nn << 8) | (nn == bc ? 1u : 0u);
            }
        }
        #pragma unroll
        for (int d2 = 1; d2 < 64; d2 <<= 1) enc |= __shfl_xor(enc, d2, 64);
        prefix = (prefix << 8) | ((enc >> 16) & 255u);
        need = (enc >> 8) & 255u;
        plen += 8;
        if (enc & 1u) { flag = true; break; }
    }

    unsigned int pos = 0;
    if (flag) {
        const int shr = 32 - plen;
        #pragma unroll
        for (int j = 0; j < 64; j++) {
            bool sel = (keys[j] >> shr) >= prefix;
            unsigned long long m = __ballot(sel);
            if (sel) orow[pos + __popcll(m & lml)] = lane + 64*j;
            pos += (unsigned int)__popcll(m);
        }
        return;
    }

    // ---- stage B: hi32 fully resolved (Hstar), r ties needed ----
    const unsigned int Hstar = prefix;
    unsigned int r = need;
    unsigned long long cand = 0ULL;
    #pragma unroll
    for (int j = 0; j < 64; j++) {
        bool gt = keys[j] > Hstar;
        unsigned long long m = __ballot(gt);
        if (gt) orow[pos + __popcll(m & lml)] = lane + 64*j;
        pos += (unsigned int)__popcll(m);
        if (keys[j] == Hstar) cand |= (1ULL << j);
    }
    // overwrite candidate keys with flipped lo32 from fp64 S
    const double* srow = S + (size_t)q * NSEQ;
    const bool negf = (Hstar >> 31) == 0u;   // flipped-hi top bit 0 => original negative
    #pragma unroll
    for (int j = 0; j < 64; j++) {
        if (cand & (1ULL << j)) {
            unsigned int lo = (unsigned int)(unsigned long long)__double_as_longlong(srow[lane + 64*j]);
            keys[j] = negf ? ~lo : lo;
        }
    }

    unsigned int prefB = 0; int plenB = 0; flag = false;
    #pragma unroll 1
    for (int p = 0; p < 4; p++) {
        *(uint4*)&hist[w][lane*4] = make_uint4(0, 0, 0, 0);
        const int sh = 24 - 8*p;
        #pragma unroll
        for (int j = 0; j < 64; j++) {
            bool act = ((cand >> j) & 1ULL) &&
                       ((((unsigned long long)keys[j]) >> (sh + 8)) == (unsigned long long)prefB);
            unsigned long long bal = __ballot(act);
            if (bal) {
                unsigned int d = (keys[j] >> sh) & 255u;
                int src = __ffsll(bal) - 1;
                unsigned int d0 = __shfl(d, src, 64);
                bool uni = (__ballot(act && d == d0) == bal);
                if (uni) { if (lane == src) atomicAdd(&hist[w][d0], (unsigned int)__popcll(bal)); }
                else if (act) atomicAdd(&hist[w][d], 1u);
            }
        }
        uint4 c = *(uint4*)&hist[w][lane*4];
        unsigned int run = c.x + c.y + c.z + c.w;
        #pragma unroll
        for (int d2 = 1; d2 < 64; d2 <<= 1) {
            unsigned int v = __shfl_down(run, d2, 64);
            if (lane + d2 < 64) run += v;
        }
        unsigned int Ss[5];
        Ss[0] = run; Ss[1] = run - c.x; Ss[2] = Ss[1] - c.y; Ss[3] = Ss[2] - c.z; Ss[4] = Ss[3] - c.w;
        unsigned int enc = 0;
        #pragma unroll
        for (int jj = 0; jj < 4; jj++) {
            if (Ss[jj] >= r && Ss[jj+1] < r) {
                unsigned int nn = r - Ss[jj+1];
                unsigned int bc = Ss[jj] - Ss[jj+1];
                enc = 0x80000000u | ((unsigned int)(lane*4 + jj) << 16) | (nn << 8) | (nn == bc ? 1u : 0u);
            }
        }
        #pragma unroll
        for (int d2 = 1; d2 < 64; d2 <<= 1) enc |= __shfl_xor(enc, d2, 64);
        prefB = (prefB << 8) | ((enc >> 16) & 255u);
        r = (enc >> 8) & 255u;
        plenB += 8;
        if (enc & 1u) { flag = true; break; }
    }

    if (flag) {
        const int shr = 32 - plenB;
        #pragma unroll
        for (int j = 0; j < 64; j++) {
            bool sel = ((cand >> j) & 1ULL) && ((keys[j] >> shr) >= prefB);
            unsigned long long m = __ballot(sel);
            if (sel) orow[pos + __popcll(m & lml)] = lane + 64*j;
            pos += (unsigned int)__popcll(m);
        }
        return;
    }
    // full 64-bit tie: strict-greater, then equals ascending by index
    const unsigned int Lstar = prefB;
    #pragma unroll
    for (int j = 0; j < 64; j++) {
        bool sel = ((cand >> j) & 1ULL) && (keys[j] > Lstar);
        unsigned long long m = __ballot(sel);
        if (sel) orow[pos + __popcll(m & lml)] = lane + 64*j;
        pos += (unsigned int)__popcll(m);
    }
    #pragma unroll
    for (int j = 0; j < 64; j++) {
        bool eq = ((cand >> j) & 1ULL) && (keys[j] == Lstar);
        unsigned long long m = __ballot(eq);
        unsigned int mypos = pos + (unsigned int)__popcll(m & lml);
        if (eq && mypos < TOPK) orow[mypos] = lane + 64*j;
        pos += (unsigned int)__popcll(m);
    }
}

// ------------------------------------------------------------------
// Attention stage 1: logits + softmax -> probs (global)
// ------------------------------------------------------------------
#define KVP 52
__global__ __launch_bounds__(256) void k_attn_qk(const float* __restrict__ Y,
                                                 const int* __restrict__ IDX,
                                                 float* __restrict__ Pr) {
    __shared__ float Ks[TOPK][KVP];
    __shared__ float qsh[NH*DKQ];
    __shared__ int   idxs[TOPK];
    const int g = blockIdx.x;
    const int b = g / NSEQ;
    const int t = threadIdx.x;

    if (t < TOPK) idxs[t] = IDX[(size_t)g*TOPK + t];
    for (int i = t; i < NH*DKQ; i += 256) qsh[i] = Y[(size_t)g*QKV_COLS + C_Q + i];
    __syncthreads();
    #pragma unroll
    for (int i = 0; i < 6; i++) {
        int e = t + 256*i;
        int j = e / 12, p = e % 12;
        const float* src = Y + (size_t)(b*NSEQ + idxs[j])*QKV_COLS + C_K;
        *(float4*)&Ks[j][p*4] = *(const float4*)(src + p*4);
    }
    __syncthreads();

    const int h  = t >> 5;
    const int j0 = t & 31;
    float lo[4] = {0.f, 0.f, 0.f, 0.f};
    #pragma unroll
    for (int c = 0; c < 12; c++) {
        float4 qv = *(const float4*)&qsh[h*DKQ + c*4];
        #pragma unroll
        for (int i = 0; i < 4; i++) {
            float4 kv = *(const float4*)&Ks[j0 + 32*i][c*4];
            lo[i] += qv.x*kv.x + qv.y*kv.y + qv.z*kv.z + qv.w*kv.w;
        }
    }
    #pragma unroll
    for (int i = 0; i < 4; i++) lo[i] *= ATT_SCALE;
    float m = fmaxf(fmaxf(lo[0], lo[1]), fmaxf(lo[2], lo[3]));
    for (int d = 16; d >= 1; d >>= 1) m = fmaxf(m, __shfl_xor(m, d, 64));
    float e0[4], sum = 0.f;
    #pragma unroll
    for (int i = 0; i < 4; i++) { e0[i] = __expf(lo[i] - m); sum += e0[i]; }
    for (int d = 16; d >= 1; d >>= 1) sum += __shfl_xor(sum, d, 64);
    float inv = 1.0f / sum;
    #pragma unroll
    for (int i = 0; i < 4; i++)
        Pr[(size_t)g*(NH*TOPK) + h*TOPK + j0 + 32*i] = e0[i] * inv;
}

// ------------------------------------------------------------------
// Attention stage 2: PV -> ctx (bf16 hi/lo split for out-proj GEMM)
// ------------------------------------------------------------------
__global__ __launch_bounds__(256) void k_attn_pv(const float* __restrict__ Y,
                                                 const int* __restrict__ IDX,
                                                 const float* __restrict__ Pr,
                                                 unsigned short* __restrict__ ctx_hi,
                                                 unsigned short* __restrict__ ctx_lo) {
    __shared__ float Vs[TOPK][KVP];
    __shared__ float prs[NH*TOPK];
    __shared__ int   idxs[TOPK];
    const int g = blockIdx.x;
    const int b = g / NSEQ;
    const int t = threadIdx.x;

    if (t < TOPK) idxs[t] = IDX[(size_t)g*TOPK + t];
    *(float4*)&prs[t*4] = *(const float4*)(Pr + (size_t)g*(NH*TOPK) + t*4);
    __syncthreads();
    #pragma unroll
    for (int i = 0; i < 6; i++) {
        int e = t + 256*i;
        int j = e / 12, p = e % 12;
        const float* src = Y + (size_t)(b*NSEQ + idxs[j])*QKV_COLS + C_V;
        *(float4*)&Vs[j][p*4] = *(const float4*)(src + p*4);
    }
    __syncthreads();

    for (int o = t; o < NH*DV; o += 256) {
        int hh = o / DV, dd = o % DV;
        float acc = 0.f;
        #pragma unroll
        for (int jc = 0; jc < 32; jc++) {
            float4 pv = *(const float4*)&prs[hh*TOPK + jc*4];
            acc += pv.x*Vs[jc*4+0][dd] + pv.y*Vs[jc*4+1][dd]
                 + pv.z*Vs[jc*4+2][dd] + pv.w*Vs[jc*4+3][dd];
        }
        unsigned short h, l;
        bsplit(acc, h, l);
        ctx_hi[(size_t)g*(NH*DV) + o] = h;
        ctx_lo[(size_t)g*(NH*DV) + o] = l;
    }
}

// ------------------------------------------------------------------
extern "C" void kernel_launch(void* const* d_in, const int* in_sizes, int n_in,
                              void* d_out, int out_size, void* d_ws, size_t ws_size,
                              hipStream_t stream) {
    const float* x      = (const float*)d_in[0];
    const float* wq_idx = (const float*)d_in[1];
    const float* wk_idx = (const float*)d_in[2];
    const float* ww_idx = (const float*)d_in[3];
    const float* wq     = (const float*)d_in[4];
    const float* wk     = (const float*)d_in[5];
    const float* wv     = (const float*)d_in[6];
    const float* wo     = (const float*)d_in[7];
    float* out = (float*)d_out;
    char*  ws  = (char*)d_ws;

    size_t off = 0;
    auto carve = [&](size_t bytes) { size_t o = off; off = (off + bytes + 255) & ~(size_t)255; return o; };
    size_t oWqh = carve((size_t)QKV_COLS*DMODEL*2);
    size_t oWql = carve((size_t)QKV_COLS*DMODEL*2);
    size_t oWoh = carve((size_t)DMODEL*DMODEL*2);
    size_t oWol = carve((size_t)DMODEL*DMODEL*2);
    size_t oWi  = carve((size_t)DMODEL*IDX_COLS*4);
    size_t oXh  = carve((size_t)NQ*DMODEL*2);
    size_t oXl  = carve((size_t)NQ*DMODEL*2);
    size_t oY   = carve((size_t)NQ*QKV_COLS*4);
    size_t oP   = carve((size_t)NQ*IDX_COLS*8);
    size_t oIdx = carve((size_t)NQ*TOPK*4);
    size_t oPr  = carve((size_t)NQ*NH*TOPK*4);
    size_t oCh  = carve((size_t)NQ*NH*DV*2);
    size_t oCl  = carve((size_t)NQ*NH*DV*2);
    size_t oS   = off;

    // chunk region: S fp64 (8 B) + K32 keys (4 B) per score
    int QC = NSEQ;
    while (QC > 32 && oS + (size_t)QC*NSEQ*12 > ws_size) QC >>= 1;

    unsigned short* WqT_hi = (unsigned short*)(ws + oWqh);
    unsigned short* WqT_lo = (unsigned short*)(ws + oWql);
    unsigned short* WoT_hi = (unsigned short*)(ws + oWoh);
    unsigned short* WoT_lo = (unsigned short*)(ws + oWol);
    float*  Wi_cat = (float*)(ws + oWi);
    unsigned short* xhi = (unsigned short*)(ws + oXh);
    unsigned short* xlo = (unsigned short*)(ws + oXl);
    float*  Y      = (float*)(ws + oY);
    double* P      = (double*)(ws + oP);
    int*    IDX    = (int*)(ws + oIdx);
    float*  Pr     = (float*)(ws + oPr);
    unsigned short* ctx_hi = (unsigned short*)(ws + oCh);
    unsigned short* ctx_lo = (unsigned short*)(ws + oCl);
    double* S      = (double*)(ws + oS);
    unsigned int* K32 = (unsigned int*)(ws + oS + (size_t)QC*NSEQ*8);

    int ncat = QKV_COLS*DMODEL + DMODEL*DMODEL + DMODEL*IDX_COLS;
    k_split<<<(NQ*DMODEL + 255)/256, 256, 0, stream>>>(x, xhi, xlo);
    k_concat<<<(ncat + 255)/256, 256, 0, stream>>>(wq_idx, wk_idx, ww_idx, wq, wk, wv, wo,
                                                   WqT_hi, WqT_lo, WoT_hi, WoT_lo, Wi_cat);
    k_gemm_mfma<<<dim3((QKV_COLS + 63)/64, NQ/128), 256, 0, stream>>>(xhi, xlo, WqT_hi, WqT_lo, Y, QKV_COLS, QKV_COLS);
    k_proj64<<<NQ/32, 256, 0, stream>>>(x, Wi_cat, P);
    for (int qs = 0; qs < NQ; qs += QC) {
        k_score_mfma<<<dim3(NSEQ/128, QC/32), 256, 0, stream>>>(P, S, K32, qs);
        k_topk_wave<<<QC/4, 256, 0, stream>>>(K32, S, IDX, qs);
    }
    k_attn_qk<<<NQ, 256, 0, stream>>>(Y, IDX, Pr);
    k_attn_pv<<<NQ, 256, 0, stream>>>(Y, IDX, Pr, ctx_hi, ctx_lo);
    k_gemm_mfma<<<dim3(DMODEL/64, NQ/128), 256, 0, stream>>>(ctx_hi, ctx_lo, WoT_hi, WoT_lo, out, DMODEL, DMODEL);
}

// Round 9
// 587.446 us; speedup vs baseline: 2.5728x; 2.5728x over previous
//
#include <hip/hip_runtime.h>
#include <math.h>

// ---- problem dims ----
#define NB 2
#define NSEQ 4096
#define DMODEL 384
#define NH 8
#define DKQ 48
#define DV 48
#define TOPK 128
#define NQ (NB*NSEQ)          // 8192 total query rows

// fp32 combined projection: [q(384) | k(48) | v(48)] = 480 cols
#define QKV_COLS 480
#define C_Q 0
#define C_K 384
#define C_V 432
// fp64 indexer projection Pd[8192][128]: [qi0(32)|qi1(32)|ki(32)|w(2)|pad]
#define IDX_COLS 128
#define P_QI 0
#define P_KI 64
#define P_W  96
#define ATT_SCALE 0.14433756729740643f   // 48^-0.5

typedef double v4d  __attribute__((ext_vector_type(4)));
typedef float  f32x4 __attribute__((ext_vector_type(4)));
typedef short  s16x8 __attribute__((ext_vector_type(8)));

// round-to-nearest-even bf16 split: v ~= hi + lo
__device__ inline void bsplit(float v, unsigned short& h, unsigned short& l) {
    unsigned hb = __float_as_uint(v);
    unsigned short hi = (unsigned short)((hb + 0x7FFFu + ((hb >> 16) & 1u)) >> 16);
    float hf = __uint_as_float(((unsigned)hi) << 16);
    float r = v - hf;
    unsigned rb = __float_as_uint(r);
    unsigned short lo = (unsigned short)((rb + 0x7FFFu + ((rb >> 16) & 1u)) >> 16);
    h = hi; l = lo;
}

// ------------------------------------------------------------------
// split x into bf16 hi/lo
// ------------------------------------------------------------------
__global__ void k_split(const float* __restrict__ x,
                        unsigned short* __restrict__ xhi, unsigned short* __restrict__ xlo) {
    int i = blockIdx.x * 256 + threadIdx.x;
    if (i < NQ * DMODEL) {
        unsigned short h, l;
        bsplit(x[i], h, l);
        xhi[i] = h; xlo[i] = l;
    }
}

// ------------------------------------------------------------------
// concat + transpose + split weights
// ------------------------------------------------------------------
__global__ void k_concat(const float* __restrict__ wq_idx, const float* __restrict__ wk_idx,
                         const float* __restrict__ ww_idx, const float* __restrict__ wq,
                         const float* __restrict__ wk, const float* __restrict__ wv,
                         const float* __restrict__ wo,
                         unsigned short* __restrict__ WqT_hi, unsigned short* __restrict__ WqT_lo,
                         unsigned short* __restrict__ WoT_hi, unsigned short* __restrict__ WoT_lo,
                         float* __restrict__ Wi_cat) {
    int i = blockIdx.x * 256 + threadIdx.x;
    const int NQK = QKV_COLS * DMODEL;          // 184320
    const int NWO = DMODEL * DMODEL;            // 147456
    if (i < NQK) {
        int n = i / DMODEL, k = i % DMODEL;
        float v;
        if (n < 384)      v = wq[(size_t)k*384 + n];
        else if (n < 432) v = wk[(size_t)k*48 + (n-384)];
        else              v = wv[(size_t)k*48 + (n-432)];
        unsigned short h, l; bsplit(v, h, l);
        WqT_hi[i] = h; WqT_lo[i] = l;
    } else if (i < NQK + NWO) {
        int j = i - NQK;
        int n = j / DMODEL, k = j % DMODEL;
        float v = wo[(size_t)k*384 + n];
        unsigned short h, l; bsplit(v, h, l);
        WoT_hi[j] = h; WoT_lo[j] = l;
    } else if (i < NQK + NWO + DMODEL*IDX_COLS) {
        int j = i - NQK - NWO;
        int d = j / IDX_COLS, c = j % IDX_COLS;
        float v;
        if (c < 64)       v = wq_idx[d*64 + c];
        else if (c < 96)  v = wk_idx[d*32 + (c-64)];
        else if (c < 98)  v = ww_idx[d*2 + (c-96)];
        else              v = 0.f;
        Wi_cat[j] = v;
    }
}

// ------------------------------------------------------------------
// split-bf16 MFMA GEMM: C[M x N] = (Ahi+Alo)[M x 384] @ (Bhi+Blo)^T
// ------------------------------------------------------------------
#define GLDK 40   // shorts per LDS row (32 + 8 pad)
__global__ __launch_bounds__(256) void k_gemm_mfma(
        const unsigned short* __restrict__ Ahi, const unsigned short* __restrict__ Alo,
        const unsigned short* __restrict__ Bhi, const unsigned short* __restrict__ Blo,
        float* __restrict__ C, int N, int ldc) {
    __shared__ unsigned short At[2][128][GLDK];
    __shared__ unsigned short Bt[2][64][GLDK];
    const int t = threadIdx.x;
    const int lane = t & 63, wid = t >> 6;
    const int row0 = blockIdx.y * 128, col0 = blockIdx.x * 64;
    const int ml = lane & 15, kq = lane >> 4;
    const int wm = (wid & 1) * 64, wn = (wid >> 1) * 32;

    // ---- layout calibration probes ----
    unsigned short mv = (unsigned short)(__float_as_uint((float)(ml + 1)) >> 16);
    unsigned short one = 0x3F80;
    s16x8 pa, pb;
    #pragma unroll
    for (int j = 0; j < 8; j++) { pa[j] = (short)mv; pb[j] = (short)one; }
    f32x4 zf = (f32x4){0.f, 0.f, 0.f, 0.f};
    f32x4 rowp = __builtin_amdgcn_mfma_f32_16x16x32_bf16(pa, pb, zf, 0, 0, 0);
    f32x4 colp = __builtin_amdgcn_mfma_f32_16x16x32_bf16(pb, pa, zf, 0, 0, 0);
    int rowm[4], colm[4];
    #pragma unroll
    for (int r = 0; r < 4; r++) {
        rowm[r] = (((int)(rowp[r] * 0.03125f + 0.5f)) - 1) & 15;
        colm[r] = (((int)(colp[r] * 0.03125f + 0.5f)) - 1) & 15;
    }

    f32x4 acc[4][2];
    #pragma unroll
    for (int mt = 0; mt < 4; mt++)
        #pragma unroll
        for (int nt = 0; nt < 2; nt++) acc[mt][nt] = zf;

    for (int k0 = 0; k0 < DMODEL; k0 += 32) {
        #pragma unroll
        for (int i = 0; i < 4; i++) {
            int ch = t + 256*i;
            int arr = ch >> 9, rem = ch & 511;
            int r = rem >> 2, p = rem & 3;
            const unsigned short* src = arr ? Alo : Ahi;
            *(int4*)&At[arr][r][p*8] = *(const int4*)(src + (size_t)(row0 + r)*DMODEL + k0 + p*8);
        }
        #pragma unroll
        for (int i = 0; i < 2; i++) {
            int ch = t + 256*i;
            int arr = ch >> 8, rem = ch & 255;
            int r = rem >> 2, p = rem & 3;
            const unsigned short* src = arr ? Blo : Bhi;
            int gc = col0 + r;
            int4 v = {0, 0, 0, 0};
            if (gc < N) v = *(const int4*)(src + (size_t)gc*DMODEL + k0 + p*8);
            *(int4*)&Bt[arr][r][p*8] = v;
        }
        __syncthreads();
        s16x8 af[4][2], bfr[2][2];
        #pragma unroll
        for (int mt = 0; mt < 4; mt++)
            #pragma unroll
            for (int h = 0; h < 2; h++)
                af[mt][h] = *(const s16x8*)&At[h][wm + mt*16 + ml][kq*8];
        #pragma unroll
        for (int nt = 0; nt < 2; nt++)
            #pragma unroll
            for (int h = 0; h < 2; h++)
                bfr[nt][h] = *(const s16x8*)&Bt[h][wn + nt*16 + ml][kq*8];
        #pragma unroll
        for (int mt = 0; mt < 4; mt++)
            #pragma unroll
            for (int nt = 0; nt < 2; nt++) {
                acc[mt][nt] = __builtin_amdgcn_mfma_f32_16x16x32_bf16(af[mt][0], bfr[nt][0], acc[mt][nt], 0, 0, 0);
                acc[mt][nt] = __builtin_amdgcn_mfma_f32_16x16x32_bf16(af[mt][0], bfr[nt][1], acc[mt][nt], 0, 0, 0);
                acc[mt][nt] = __builtin_amdgcn_mfma_f32_16x16x32_bf16(af[mt][1], bfr[nt][0], acc[mt][nt], 0, 0, 0);
            }
        __syncthreads();
    }
    #pragma unroll
    for (int mt = 0; mt < 4; mt++)
        #pragma unroll
        for (int nt = 0; nt < 2; nt++)
            #pragma unroll
            for (int r = 0; r < 4; r++) {
                int rr = row0 + wm + mt*16 + rowm[r];
                int cc = col0 + wn + nt*16 + colm[r];
                if (cc < N) C[(size_t)rr*ldc + cc] = acc[mt][nt][r];
            }
}

// ------------------------------------------------------------------
// fp64-accumulated indexer projection: Pd[8192][128] = x @ Wi_cat
// ------------------------------------------------------------------
__global__ __launch_bounds__(256) void k_proj64(const float* __restrict__ A,
                                                const float* __restrict__ W,
                                                double* __restrict__ P) {
    __shared__ float At[16][32];
    __shared__ float Bt[16][IDX_COLS];
    const int t  = threadIdx.x;
    const int tx = t & 15;
    const int ty = t >> 4;
    const int row0 = blockIdx.x * 32;
    double acc[2][8] = {};

    for (int k0 = 0; k0 < DMODEL; k0 += 16) {
        if (t < 128) {
            int m = t >> 2, kc = t & 3;
            float4 a = *(const float4*)(A + (size_t)(row0 + m)*DMODEL + k0 + kc*4);
            At[kc*4+0][m] = a.x; At[kc*4+1][m] = a.y;
            At[kc*4+2][m] = a.z; At[kc*4+3][m] = a.w;
        }
        for (int i = 0; i < 2; i++) {
            int lin = t + i*256;
            int kk = lin >> 5, c4 = lin & 31;
            float4 b = *(const float4*)(W + (size_t)(k0+kk)*IDX_COLS + c4*4);
            *(float4*)&Bt[kk][c4*4] = b;
        }
        __syncthreads();
        for (int kk = 0; kk < 16; kk++) {
            float a2[2], b8[8];
            a2[0] = At[kk][ty*2]; a2[1] = At[kk][ty*2+1];
            *(float4*)&b8[0] = *(const float4*)&Bt[kk][tx*8];
            *(float4*)&b8[4] = *(const float4*)&Bt[kk][tx*8+4];
            for (int i = 0; i < 2; i++)
                for (int j = 0; j < 8; j++)
                    acc[i][j] += (double)a2[i] * (double)b8[j];
        }
        __syncthreads();
    }
    for (int i = 0; i < 2; i++)
        for (int j = 0; j < 8; j++)
            P[(size_t)(row0 + ty*2 + i)*IDX_COLS + tx*8 + j] = acc[i][j];
}

// ------------------------------------------------------------------
// fp64 index scores via MFMA f64 16x16x4, self-calibrated C/D layout.
// Emits the bias-flipped sortable u64 key split as K32 (hi) / L32 (lo).
// No fp64 score array is materialized.
// ------------------------------------------------------------------
__global__ __launch_bounds__(256) void k_score_mfma(const double* __restrict__ P,
                                                    unsigned int* __restrict__ K32,
                                                    unsigned int* __restrict__ L32,
                                                    int qstart) {
    __shared__ double A0[32][33];
    __shared__ double A1[32][33];
    __shared__ double Bk[32][129];
    __shared__ double wsh[2][32];
    const int t = threadIdx.x;
    const int lane = t & 63;
    const int wid = t >> 6;
    const int g0 = qstart + blockIdx.y * 32;
    const int b  = g0 / NSEQ;
    const int s0 = blockIdx.x * 128;

    for (int i = 0; i < 8; i++) {
        int lin = t + i*256;
        int q = lin >> 6, c = lin & 63;
        double v = P[(size_t)(g0 + q)*IDX_COLS + P_QI + c];
        if (c < 32) A0[c][q] = v; else A1[c-32][q] = v;
    }
    for (int i = 0; i < 16; i++) {
        int lin = t + i*256;
        int s = lin >> 5, c = lin & 31;
        Bk[c][s] = P[(size_t)(b*NSEQ + s0 + s)*IDX_COLS + P_KI + c];
    }
    if (t < 64) wsh[t & 1][t >> 1] = P[(size_t)(g0 + (t >> 1))*IDX_COLS + P_W + (t & 1)];

    const int qw = (wid & 1) * 16;
    const int sw = (wid >> 1) * 64;
    const int ml = lane & 15;
    const int kl = lane >> 4;

    v4d zero = (v4d){0.0, 0.0, 0.0, 0.0};
    v4d rowp = __builtin_amdgcn_mfma_f64_16x16x4f64((double)(ml+1), 1.0, zero, 0, 0, 0);
    v4d colp = __builtin_amdgcn_mfma_f64_16x16x4f64(1.0, (double)(ml+1), zero, 0, 0, 0);
    int rowm[4], colm[4];
    #pragma unroll
    for (int r = 0; r < 4; r++) {
        rowm[r] = (((int)(rowp[r] * 0.25 + 0.5)) - 1) & 15;
        colm[r] = (((int)(colp[r] * 0.25 + 0.5)) - 1) & 15;
    }

    __syncthreads();

    v4d acc0[4], acc1[4];
    #pragma unroll
    for (int st = 0; st < 4; st++) { acc0[st] = zero; acc1[st] = zero; }

    #pragma unroll
    for (int k4 = 0; k4 < 8; k4++) {
        int k = k4*4 + kl;
        double a0 = A0[k][qw + ml];
        double a1 = A1[k][qw + ml];
        #pragma unroll
        for (int st = 0; st < 4; st++) {
            double bb = Bk[k][sw + st*16 + ml];
            acc0[st] = __builtin_amdgcn_mfma_f64_16x16x4f64(a0, bb, acc0[st], 0, 0, 0);
            acc1[st] = __builtin_amdgcn_mfma_f64_16x16x4f64(a1, bb, acc1[st], 0, 0, 0);
        }
    }

    #pragma unroll
    for (int reg = 0; reg < 4; reg++) {
        int q = qw + rowm[reg];
        double w0 = wsh[0][q], w1 = wsh[1][q];
        #pragma unroll
        for (int st = 0; st < 4; st++) {
            double sc = w0 * fmax(acc0[st][reg], 0.0) + w1 * fmax(acc1[st][reg], 0.0);
            size_t oidx = (size_t)(blockIdx.y*32 + q)*NSEQ + s0 + sw + st*16 + colm[reg];
            unsigned long long bb = (unsigned long long)__double_as_longlong(sc);
            unsigned long long u = (bb & 0x8000000000000000ULL) ? ~bb : (bb | 0x8000000000000000ULL);
            K32[oidx] = (unsigned int)(u >> 32);
            L32[oidx] = (unsigned int)u;
        }
    }
}

// ------------------------------------------------------------------
// Block-per-query top-128 (round-7 proven structure): hi32 radix
// select w/ early exit from precomputed K32; L32 only on hi-ties.
// ------------------------------------------------------------------
__global__ __launch_bounds__(256) void k_topk(const unsigned int* __restrict__ K32,
                                              const unsigned int* __restrict__ L32,
                                              int* __restrict__ IDX, int qstart) {
    __shared__ unsigned int key[NSEQ + NSEQ/16];
    __shared__ unsigned int candMask[NSEQ/32];
    __shared__ unsigned int hist[256];
    __shared__ unsigned int s_ph, s_need, s_flag, s_cnt;
    __shared__ unsigned int wsum[4];
    const int t = threadIdx.x;
    const int lane = t & 63;
    const int wid = t >> 6;
    const int q = blockIdx.x;
    const unsigned int* krow = K32 + (size_t)q * NSEQ;
    const unsigned int* lrow = L32 + (size_t)q * NSEQ;
    int* orow = IDX + (size_t)(qstart + q) * TOPK;

    auto pad = [](int i) { return i + (i >> 4); };

    auto decide = [&]() {
        if (wid == 0) {
            unsigned int c0 = hist[lane*4+0], c1 = hist[lane*4+1],
                         c2 = hist[lane*4+2], c3 = hist[lane*4+3];
            unsigned int run = c0 + c1 + c2 + c3;
            for (int d = 1; d < 64; d <<= 1) {
                unsigned int v = __shfl_down(run, d, 64);
                if (lane + d < 64) run += v;
            }
            unsigned int need = s_need;
            unsigned int Sb[5];
            Sb[0] = run;
            Sb[1] = run - c0;
            Sb[2] = Sb[1] - c1;
            Sb[3] = Sb[2] - c2;
            Sb[4] = Sb[3] - c3;
            for (int j = 0; j < 4; j++) {
                if (Sb[j] >= need && Sb[j+1] < need) {
                    unsigned int digit   = (unsigned int)(lane*4 + j);
                    unsigned int newneed = need - Sb[j+1];
                    unsigned int binCnt  = Sb[j] - Sb[j+1];
                    s_ph   = (s_ph << 8) | digit;
                    s_need = newneed;
                    if (newneed == binCnt) s_flag = 1;
                }
            }
        }
        __syncthreads();
    };

    hist[t] = 0;
    if (t == 0) { s_ph = 0; s_need = TOPK; s_flag = 0; s_cnt = 0; }
    __syncthreads();
    for (int j = 0; j < 16; j++) {
        int i = t + 256*j;
        unsigned int h = krow[i];
        key[pad(i)] = h;
        atomicAdd(&hist[h >> 24], 1u);
    }
    __syncthreads();

    decide();
    int plen = 8;
    for (int p = 1; p < 4; p++) {
        if (s_flag) break;
        const int sh = 24 - 8*p;
        hist[t] = 0;
        __syncthreads();
        unsigned int ph = s_ph;
        for (int j = 0; j < 16; j++) {
            int i = t*16 + j;
            unsigned int h = key[pad(i)];
            if ((h >> (sh+8)) == ph) atomicAdd(&hist[(h >> sh) & 255u], 1u);
        }
        __syncthreads();
        decide();
        plen += 8;
    }

    if (s_flag) {
        unsigned int P = s_ph;
        int shr = 32 - plen;
        for (int j = 0; j < 16; j++) {
            int i = t*16 + j;
            unsigned int h = key[pad(i)];
            if ((h >> shr) >= P) {
                unsigned int pos = atomicAdd(&s_cnt, 1u);
                orow[pos] = i;
            }
        }
        return;
    }

    unsigned int Hstar = s_ph;
    if (t < 128) candMask[t] = 0;
    __syncthreads();
    if (t == 0) s_ph = 0;
    for (int j = 0; j < 16; j++) {
        int i = t + 256*j;
        unsigned int h = key[pad(i)];
        if (h > Hstar) {
            unsigned int pos = atomicAdd(&s_cnt, 1u);
            orow[pos] = i;
        } else if (h == Hstar) {
            atomicOr(&candMask[i >> 5], 1u << (i & 31));
            key[pad(i)] = lrow[i];
        }
    }
    __syncthreads();

    int plenB = 0;
    for (int p = 0; p < 4; p++) {
        if (s_flag) break;
        const int sh = 24 - 8*p;
        hist[t] = 0;
        __syncthreads();
        unsigned int ph = s_ph;
        for (int j = 0; j < 16; j++) {
            int i = t*16 + j;
            if (candMask[i >> 5] & (1u << (i & 31))) {
                unsigned int h = key[pad(i)];
                if (p == 0 || (h >> (sh+8)) == ph) atomicAdd(&hist[(h >> sh) & 255u], 1u);
            }
        }
        __syncthreads();
        decide();
        plenB += 8;
    }

    if (s_flag) {
        unsigned int P = s_ph;
        int shr = 32 - plenB;
        for (int j = 0; j < 16; j++) {
            int i = t*16 + j;
            if (candMask[i >> 5] & (1u << (i & 31))) {
                unsigned int h = key[pad(i)];
                if ((h >> shr) >= P) {
                    unsigned int pos = atomicAdd(&s_cnt, 1u);
                    orow[pos] = i;
                }
            }
        }
        return;
    }

    unsigned int Lstar = s_ph;
    unsigned int r = s_need;
    unsigned int cnt = 0;
    for (int j = 0; j < 16; j++) {
        int i = t*16 + j;
        if (candMask[i >> 5] & (1u << (i & 31))) {
            unsigned int h = key[pad(i)];
            if (h > Lstar) {
                unsigned int pos = atomicAdd(&s_cnt, 1u);
                orow[pos] = i;
            } else if (h == Lstar) cnt++;
        }
    }
    unsigned int inc = cnt;
    for (int d = 1; d < 64; d <<= 1) {
        unsigned int v = __shfl_up(inc, d, 64);
        if (lane >= d) inc += v;
    }
    if (lane == 63) wsum[wid] = inc;
    __syncthreads();
    unsigned int woff = 0;
    for (int w2 = 0; w2 < wid; w2++) woff += wsum[w2];
    unsigned int rk = woff + inc - cnt;
    unsigned int tbase = TOPK - r;
    for (int j = 0; j < 16; j++) {
        int i = t*16 + j;
        if (candMask[i >> 5] & (1u << (i & 31))) {
            unsigned int h = key[pad(i)];
            if (h == Lstar) {
                if (rk < r) orow[tbase + rk] = i;
                rk++;
            }
        }
    }
}

// ------------------------------------------------------------------
// Attention stage 1: logits + softmax -> probs (global)
// ------------------------------------------------------------------
#define KVP 52
__global__ __launch_bounds__(256) void k_attn_qk(const float* __restrict__ Y,
                                                 const int* __restrict__ IDX,
                                                 float* __restrict__ Pr) {
    __shared__ float Ks[TOPK][KVP];
    __shared__ float qsh[NH*DKQ];
    __shared__ int   idxs[TOPK];
    const int g = blockIdx.x;
    const int b = g / NSEQ;
    const int t = threadIdx.x;

    if (t < TOPK) idxs[t] = IDX[(size_t)g*TOPK + t];
    for (int i = t; i < NH*DKQ; i += 256) qsh[i] = Y[(size_t)g*QKV_COLS + C_Q + i];
    __syncthreads();
    #pragma unroll
    for (int i = 0; i < 6; i++) {
        int e = t + 256*i;
        int j = e / 12, p = e % 12;
        const float* src = Y + (size_t)(b*NSEQ + idxs[j])*QKV_COLS + C_K;
        *(float4*)&Ks[j][p*4] = *(const float4*)(src + p*4);
    }
    __syncthreads();

    const int h  = t >> 5;
    const int j0 = t & 31;
    float lo[4] = {0.f, 0.f, 0.f, 0.f};
    #pragma unroll
    for (int c = 0; c < 12; c++) {
        float4 qv = *(const float4*)&qsh[h*DKQ + c*4];
        #pragma unroll
        for (int i = 0; i < 4; i++) {
            float4 kv = *(const float4*)&Ks[j0 + 32*i][c*4];
            lo[i] += qv.x*kv.x + qv.y*kv.y + qv.z*kv.z + qv.w*kv.w;
        }
    }
    #pragma unroll
    for (int i = 0; i < 4; i++) lo[i] *= ATT_SCALE;
    float m = fmaxf(fmaxf(lo[0], lo[1]), fmaxf(lo[2], lo[3]));
    for (int d = 16; d >= 1; d >>= 1) m = fmaxf(m, __shfl_xor(m, d, 64));
    float e0[4], sum = 0.f;
    #pragma unroll
    for (int i = 0; i < 4; i++) { e0[i] = __expf(lo[i] - m); sum += e0[i]; }
    for (int d = 16; d >= 1; d >>= 1) sum += __shfl_xor(sum, d, 64);
    float inv = 1.0f / sum;
    #pragma unroll
    for (int i = 0; i < 4; i++)
        Pr[(size_t)g*(NH*TOPK) + h*TOPK + j0 + 32*i] = e0[i] * inv;
}

// ------------------------------------------------------------------
// Attention stage 2: PV -> ctx (bf16 hi/lo split for out-proj GEMM)
// ------------------------------------------------------------------
__global__ __launch_bounds__(256) void k_attn_pv(const float* __restrict__ Y,
                                                 const int* __restrict__ IDX,
                                                 const float* __restrict__ Pr,
                                                 unsigned short* __restrict__ ctx_hi,
                                                 unsigned short* __restrict__ ctx_lo) {
    __shared__ float Vs[TOPK][KVP];
    __shared__ float prs[NH*TOPK];
    __shared__ int   idxs[TOPK];
    const int g = blockIdx.x;
    const int b = g / NSEQ;
    const int t = threadIdx.x;

    if (t < TOPK) idxs[t] = IDX[(size_t)g*TOPK + t];
    *(float4*)&prs[t*4] = *(const float4*)(Pr + (size_t)g*(NH*TOPK) + t*4);
    __syncthreads();
    #pragma unroll
    for (int i = 0; i < 6; i++) {
        int e = t + 256*i;
        int j = e / 12, p = e % 12;
        const float* src = Y + (size_t)(b*NSEQ + idxs[j])*QKV_COLS + C_V;
        *(float4*)&Vs[j][p*4] = *(const float4*)(src + p*4);
    }
    __syncthreads();

    for (int o = t; o < NH*DV; o += 256) {
        int hh = o / DV, dd = o % DV;
        float acc = 0.f;
        #pragma unroll
        for (int jc = 0; jc < 32; jc++) {
            float4 pv = *(const float4*)&prs[hh*TOPK + jc*4];
            acc += pv.x*Vs[jc*4+0][dd] + pv.y*Vs[jc*4+1][dd]
                 + pv.z*Vs[jc*4+2][dd] + pv.w*Vs[jc*4+3][dd];
        }
        unsigned short h, l;
        bsplit(acc, h, l);
        ctx_hi[(size_t)g*(NH*DV) + o] = h;
        ctx_lo[(size_t)g*(NH*DV) + o] = l;
    }
}

// ------------------------------------------------------------------
extern "C" void kernel_launch(void* const* d_in, const int* in_sizes, int n_in,
                              void* d_out, int out_size, void* d_ws, size_t ws_size,
                              hipStream_t stream) {
    const float* x      = (const float*)d_in[0];
    const float* wq_idx = (const float*)d_in[1];
    const float* wk_idx = (const float*)d_in[2];
    const float* ww_idx = (const float*)d_in[3];
    const float* wq     = (const float*)d_in[4];
    const float* wk     = (const float*)d_in[5];
    const float* wv     = (const float*)d_in[6];
    const float* wo     = (const float*)d_in[7];
    float* out = (float*)d_out;
    char*  ws  = (char*)d_ws;

    size_t off = 0;
    auto carve = [&](size_t bytes) { size_t o = off; off = (off + bytes + 255) & ~(size_t)255; return o; };
    size_t oWqh = carve((size_t)QKV_COLS*DMODEL*2);
    size_t oWql = carve((size_t)QKV_COLS*DMODEL*2);
    size_t oWoh = carve((size_t)DMODEL*DMODEL*2);
    size_t oWol = carve((size_t)DMODEL*DMODEL*2);
    size_t oWi  = carve((size_t)DMODEL*IDX_COLS*4);
    size_t oXh  = carve((size_t)NQ*DMODEL*2);
    size_t oXl  = carve((size_t)NQ*DMODEL*2);
    size_t oY   = carve((size_t)NQ*QKV_COLS*4);
    size_t oP   = carve((size_t)NQ*IDX_COLS*8);
    size_t oIdx = carve((size_t)NQ*TOPK*4);
    size_t oPr  = carve((size_t)NQ*NH*TOPK*4);
    size_t oCh  = carve((size_t)NQ*NH*DV*2);
    size_t oCl  = carve((size_t)NQ*NH*DV*2);
    size_t oKL  = off;

    // chunk region: K32 (4 B) + L32 (4 B) per score
    int QC = NSEQ;
    while (QC > 32 && oKL + (size_t)QC*NSEQ*8 > ws_size) QC >>= 1;

    unsigned short* WqT_hi = (unsigned short*)(ws + oWqh);
    unsigned short* WqT_lo = (unsigned short*)(ws + oWql);
    unsigned short* WoT_hi = (unsigned short*)(ws + oWoh);
    unsigned short* WoT_lo = (unsigned short*)(ws + oWol);
    float*  Wi_cat = (float*)(ws + oWi);
    unsigned short* xhi = (unsigned short*)(ws + oXh);
    unsigned short* xlo = (unsigned short*)(ws + oXl);
    float*  Y      = (float*)(ws + oY);
    double* P      = (double*)(ws + oP);
    int*    IDX    = (int*)(ws + oIdx);
    float*  Pr     = (float*)(ws + oPr);
    unsigned short* ctx_hi = (unsigned short*)(ws + oCh);
    unsigned short* ctx_lo = (unsigned short*)(ws + oCl);
    unsigned int* K32 = (unsigned int*)(ws + oKL);
    unsigned int* L32 = (unsigned int*)(ws + oKL + (size_t)QC*NSEQ*4);

    int ncat = QKV_COLS*DMODEL + DMODEL*DMODEL + DMODEL*IDX_COLS;
    k_split<<<(NQ*DMODEL + 255)/256, 256, 0, stream>>>(x, xhi, xlo);
    k_concat<<<(ncat + 255)/256, 256, 0, stream>>>(wq_idx, wk_idx, ww_idx, wq, wk, wv, wo,
                                                   WqT_hi, WqT_lo, WoT_hi, WoT_lo, Wi_cat);
    k_gemm_mfma<<<dim3((QKV_COLS + 63)/64, NQ/128), 256, 0, stream>>>(xhi, xlo, WqT_hi, WqT_lo, Y, QKV_COLS, QKV_COLS);
    k_proj64<<<NQ/32, 256, 0, stream>>>(x, Wi_cat, P);
    for (int qs = 0; qs < NQ; qs += QC) {
        k_score_mfma<<<dim3(NSEQ/128, QC/32), 256, 0, stream>>>(P, K32, L32, qs);
        k_topk<<<QC, 256, 0, stream>>>(K32, L32, IDX, qs);
    }
    k_attn_qk<<<NQ, 256, 0, stream>>>(Y, IDX, Pr);
    k_attn_pv<<<NQ, 256, 0, stream>>>(Y, IDX, Pr, ctx_hi, ctx_lo);
    k_gemm_mfma<<<dim3(DMODEL/64, NQ/128), 256, 0, stream>>>(ctx_hi, ctx_lo, WoT_hi, WoT_lo, out, DMODEL, DMODEL);
}

// Round 10
// 583.221 us; speedup vs baseline: 2.5914x; 1.0072x over previous
//
#include <hip/hip_runtime.h>
#include <math.h>

// ---- problem dims ----
#define NB 2
#define NSEQ 4096
#define DMODEL 384
#define NH 8
#define DKQ 48
#define DV 48
#define TOPK 128
#define NQ (NB*NSEQ)          // 8192 total query rows

// fp32 combined projection: [q(384) | k(48) | v(48)] = 480 cols
#define QKV_COLS 480
#define C_Q 0
#define C_K 384
#define C_V 432
// fp64 indexer projection Pd[8192][128]: [qi0(32)|qi1(32)|ki(32)|w(2)|pad]
#define IDX_COLS 128
#define P_QI 0
#define P_KI 64
#define P_W  96
#define ATT_SCALE 0.14433756729740643f   // 48^-0.5

typedef double v4d  __attribute__((ext_vector_type(4)));
typedef float  f32x4 __attribute__((ext_vector_type(4)));
typedef short  s16x8 __attribute__((ext_vector_type(8)));

// round-to-nearest-even bf16 split: v ~= hi + lo
__device__ inline void bsplit(float v, unsigned short& h, unsigned short& l) {
    unsigned hb = __float_as_uint(v);
    unsigned short hi = (unsigned short)((hb + 0x7FFFu + ((hb >> 16) & 1u)) >> 16);
    float hf = __uint_as_float(((unsigned)hi) << 16);
    float r = v - hf;
    unsigned rb = __float_as_uint(r);
    unsigned short lo = (unsigned short)((rb + 0x7FFFu + ((rb >> 16) & 1u)) >> 16);
    h = hi; l = lo;
}

// ------------------------------------------------------------------
// split x into bf16 hi/lo
// ------------------------------------------------------------------
__global__ void k_split(const float* __restrict__ x,
                        unsigned short* __restrict__ xhi, unsigned short* __restrict__ xlo) {
    int i = blockIdx.x * 256 + threadIdx.x;
    if (i < NQ * DMODEL) {
        unsigned short h, l;
        bsplit(x[i], h, l);
        xhi[i] = h; xlo[i] = l;
    }
}

// ------------------------------------------------------------------
// concat + transpose + split weights
// ------------------------------------------------------------------
__global__ void k_concat(const float* __restrict__ wq_idx, const float* __restrict__ wk_idx,
                         const float* __restrict__ ww_idx, const float* __restrict__ wq,
                         const float* __restrict__ wk, const float* __restrict__ wv,
                         const float* __restrict__ wo,
                         unsigned short* __restrict__ WqT_hi, unsigned short* __restrict__ WqT_lo,
                         unsigned short* __restrict__ WoT_hi, unsigned short* __restrict__ WoT_lo,
                         float* __restrict__ Wi_cat) {
    int i = blockIdx.x * 256 + threadIdx.x;
    const int NQK = QKV_COLS * DMODEL;          // 184320
    const int NWO = DMODEL * DMODEL;            // 147456
    if (i < NQK) {
        int n = i / DMODEL, k = i % DMODEL;
        float v;
        if (n < 384)      v = wq[(size_t)k*384 + n];
        else if (n < 432) v = wk[(size_t)k*48 + (n-384)];
        else              v = wv[(size_t)k*48 + (n-432)];
        unsigned short h, l; bsplit(v, h, l);
        WqT_hi[i] = h; WqT_lo[i] = l;
    } else if (i < NQK + NWO) {
        int j = i - NQK;
        int n = j / DMODEL, k = j % DMODEL;
        float v = wo[(size_t)k*384 + n];
        unsigned short h, l; bsplit(v, h, l);
        WoT_hi[j] = h; WoT_lo[j] = l;
    } else if (i < NQK + NWO + DMODEL*IDX_COLS) {
        int j = i - NQK - NWO;
        int d = j / IDX_COLS, c = j % IDX_COLS;
        float v;
        if (c < 64)       v = wq_idx[d*64 + c];
        else if (c < 96)  v = wk_idx[d*32 + (c-64)];
        else if (c < 98)  v = ww_idx[d*2 + (c-96)];
        else              v = 0.f;
        Wi_cat[j] = v;
    }
}

// ------------------------------------------------------------------
// split-bf16 MFMA GEMM: C[M x N] = (Ahi+Alo)[M x 384] @ (Bhi+Blo)^T
// ------------------------------------------------------------------
#define GLDK 40   // shorts per LDS row (32 + 8 pad)
__global__ __launch_bounds__(256) void k_gemm_mfma(
        const unsigned short* __restrict__ Ahi, const unsigned short* __restrict__ Alo,
        const unsigned short* __restrict__ Bhi, const unsigned short* __restrict__ Blo,
        float* __restrict__ C, int N, int ldc) {
    __shared__ unsigned short At[2][128][GLDK];
    __shared__ unsigned short Bt[2][64][GLDK];
    const int t = threadIdx.x;
    const int lane = t & 63, wid = t >> 6;
    const int row0 = blockIdx.y * 128, col0 = blockIdx.x * 64;
    const int ml = lane & 15, kq = lane >> 4;
    const int wm = (wid & 1) * 64, wn = (wid >> 1) * 32;

    // ---- layout calibration probes ----
    unsigned short mv = (unsigned short)(__float_as_uint((float)(ml + 1)) >> 16);
    unsigned short one = 0x3F80;
    s16x8 pa, pb;
    #pragma unroll
    for (int j = 0; j < 8; j++) { pa[j] = (short)mv; pb[j] = (short)one; }
    f32x4 zf = (f32x4){0.f, 0.f, 0.f, 0.f};
    f32x4 rowp = __builtin_amdgcn_mfma_f32_16x16x32_bf16(pa, pb, zf, 0, 0, 0);
    f32x4 colp = __builtin_amdgcn_mfma_f32_16x16x32_bf16(pb, pa, zf, 0, 0, 0);
    int rowm[4], colm[4];
    #pragma unroll
    for (int r = 0; r < 4; r++) {
        rowm[r] = (((int)(rowp[r] * 0.03125f + 0.5f)) - 1) & 15;
        colm[r] = (((int)(colp[r] * 0.03125f + 0.5f)) - 1) & 15;
    }

    f32x4 acc[4][2];
    #pragma unroll
    for (int mt = 0; mt < 4; mt++)
        #pragma unroll
        for (int nt = 0; nt < 2; nt++) acc[mt][nt] = zf;

    for (int k0 = 0; k0 < DMODEL; k0 += 32) {
        #pragma unroll
        for (int i = 0; i < 4; i++) {
            int ch = t + 256*i;
            int arr = ch >> 9, rem = ch & 511;
            int r = rem >> 2, p = rem & 3;
            const unsigned short* src = arr ? Alo : Ahi;
            *(int4*)&At[arr][r][p*8] = *(const int4*)(src + (size_t)(row0 + r)*DMODEL + k0 + p*8);
        }
        #pragma unroll
        for (int i = 0; i < 2; i++) {
            int ch = t + 256*i;
            int arr = ch >> 8, rem = ch & 255;
            int r = rem >> 2, p = rem & 3;
            const unsigned short* src = arr ? Blo : Bhi;
            int gc = col0 + r;
            int4 v = {0, 0, 0, 0};
            if (gc < N) v = *(const int4*)(src + (size_t)gc*DMODEL + k0 + p*8);
            *(int4*)&Bt[arr][r][p*8] = v;
        }
        __syncthreads();
        s16x8 af[4][2], bfr[2][2];
        #pragma unroll
        for (int mt = 0; mt < 4; mt++)
            #pragma unroll
            for (int h = 0; h < 2; h++)
                af[mt][h] = *(const s16x8*)&At[h][wm + mt*16 + ml][kq*8];
        #pragma unroll
        for (int nt = 0; nt < 2; nt++)
            #pragma unroll
            for (int h = 0; h < 2; h++)
                bfr[nt][h] = *(const s16x8*)&Bt[h][wn + nt*16 + ml][kq*8];
        #pragma unroll
        for (int mt = 0; mt < 4; mt++)
            #pragma unroll
            for (int nt = 0; nt < 2; nt++) {
                acc[mt][nt] = __builtin_amdgcn_mfma_f32_16x16x32_bf16(af[mt][0], bfr[nt][0], acc[mt][nt], 0, 0, 0);
                acc[mt][nt] = __builtin_amdgcn_mfma_f32_16x16x32_bf16(af[mt][0], bfr[nt][1], acc[mt][nt], 0, 0, 0);
                acc[mt][nt] = __builtin_amdgcn_mfma_f32_16x16x32_bf16(af[mt][1], bfr[nt][0], acc[mt][nt], 0, 0, 0);
            }
        __syncthreads();
    }
    #pragma unroll
    for (int mt = 0; mt < 4; mt++)
        #pragma unroll
        for (int nt = 0; nt < 2; nt++)
            #pragma unroll
            for (int r = 0; r < 4; r++) {
                int rr = row0 + wm + mt*16 + rowm[r];
                int cc = col0 + wn + nt*16 + colm[r];
                if (cc < N) C[(size_t)rr*ldc + cc] = acc[mt][nt][r];
            }
}

// ------------------------------------------------------------------
// fp64-accumulated indexer projection: Pd[8192][128] = x @ Wi_cat
// ------------------------------------------------------------------
__global__ __launch_bounds__(256) void k_proj64(const float* __restrict__ A,
                                                const float* __restrict__ W,
                                                double* __restrict__ P) {
    __shared__ float At[16][32];
    __shared__ float Bt[16][IDX_COLS];
    const int t  = threadIdx.x;
    const int tx = t & 15;
    const int ty = t >> 4;
    const int row0 = blockIdx.x * 32;
    double acc[2][8] = {};

    for (int k0 = 0; k0 < DMODEL; k0 += 16) {
        if (t < 128) {
            int m = t >> 2, kc = t & 3;
            float4 a = *(const float4*)(A + (size_t)(row0 + m)*DMODEL + k0 + kc*4);
            At[kc*4+0][m] = a.x; At[kc*4+1][m] = a.y;
            At[kc*4+2][m] = a.z; At[kc*4+3][m] = a.w;
        }
        for (int i = 0; i < 2; i++) {
            int lin = t + i*256;
            int kk = lin >> 5, c4 = lin & 31;
            float4 b = *(const float4*)(W + (size_t)(k0+kk)*IDX_COLS + c4*4);
            *(float4*)&Bt[kk][c4*4] = b;
        }
        __syncthreads();
        for (int kk = 0; kk < 16; kk++) {
            float a2[2], b8[8];
            a2[0] = At[kk][ty*2]; a2[1] = At[kk][ty*2+1];
            *(float4*)&b8[0] = *(const float4*)&Bt[kk][tx*8];
            *(float4*)&b8[4] = *(const float4*)&Bt[kk][tx*8+4];
            for (int i = 0; i < 2; i++)
                for (int j = 0; j < 8; j++)
                    acc[i][j] += (double)a2[i] * (double)b8[j];
        }
        __syncthreads();
    }
    for (int i = 0; i < 2; i++)
        for (int j = 0; j < 8; j++)
            P[(size_t)(row0 + ty*2 + i)*IDX_COLS + tx*8 + j] = acc[i][j];
}

// ------------------------------------------------------------------
// fp64 index scores via MFMA f64 16x16x4, self-calibrated C/D layout.
// Emits bias-flipped sortable u64 key split as K32 (hi) / L32 (lo).
// ------------------------------------------------------------------
__global__ __launch_bounds__(256) void k_score_mfma(const double* __restrict__ P,
                                                    unsigned int* __restrict__ K32,
                                                    unsigned int* __restrict__ L32,
                                                    int qstart) {
    __shared__ double A0[32][33];
    __shared__ double A1[32][33];
    __shared__ double Bk[32][129];
    __shared__ double wsh[2][32];
    const int t = threadIdx.x;
    const int lane = t & 63;
    const int wid = t >> 6;
    const int g0 = qstart + blockIdx.y * 32;
    const int b  = g0 / NSEQ;
    const int s0 = blockIdx.x * 128;

    for (int i = 0; i < 8; i++) {
        int lin = t + i*256;
        int q = lin >> 6, c = lin & 63;
        double v = P[(size_t)(g0 + q)*IDX_COLS + P_QI + c];
        if (c < 32) A0[c][q] = v; else A1[c-32][q] = v;
    }
    for (int i = 0; i < 16; i++) {
        int lin = t + i*256;
        int s = lin >> 5, c = lin & 31;
        Bk[c][s] = P[(size_t)(b*NSEQ + s0 + s)*IDX_COLS + P_KI + c];
    }
    if (t < 64) wsh[t & 1][t >> 1] = P[(size_t)(g0 + (t >> 1))*IDX_COLS + P_W + (t & 1)];

    const int qw = (wid & 1) * 16;
    const int sw = (wid >> 1) * 64;
    const int ml = lane & 15;
    const int kl = lane >> 4;

    v4d zero = (v4d){0.0, 0.0, 0.0, 0.0};
    v4d rowp = __builtin_amdgcn_mfma_f64_16x16x4f64((double)(ml+1), 1.0, zero, 0, 0, 0);
    v4d colp = __builtin_amdgcn_mfma_f64_16x16x4f64(1.0, (double)(ml+1), zero, 0, 0, 0);
    int rowm[4], colm[4];
    #pragma unroll
    for (int r = 0; r < 4; r++) {
        rowm[r] = (((int)(rowp[r] * 0.25 + 0.5)) - 1) & 15;
        colm[r] = (((int)(colp[r] * 0.25 + 0.5)) - 1) & 15;
    }

    __syncthreads();

    v4d acc0[4], acc1[4];
    #pragma unroll
    for (int st = 0; st < 4; st++) { acc0[st] = zero; acc1[st] = zero; }

    #pragma unroll
    for (int k4 = 0; k4 < 8; k4++) {
        int k = k4*4 + kl;
        double a0 = A0[k][qw + ml];
        double a1 = A1[k][qw + ml];
        #pragma unroll
        for (int st = 0; st < 4; st++) {
            double bb = Bk[k][sw + st*16 + ml];
            acc0[st] = __builtin_amdgcn_mfma_f64_16x16x4f64(a0, bb, acc0[st], 0, 0, 0);
            acc1[st] = __builtin_amdgcn_mfma_f64_16x16x4f64(a1, bb, acc1[st], 0, 0, 0);
        }
    }

    #pragma unroll
    for (int reg = 0; reg < 4; reg++) {
        int q = qw + rowm[reg];
        double w0 = wsh[0][q], w1 = wsh[1][q];
        #pragma unroll
        for (int st = 0; st < 4; st++) {
            double sc = w0 * fmax(acc0[st][reg], 0.0) + w1 * fmax(acc1[st][reg], 0.0);
            size_t oidx = (size_t)(blockIdx.y*32 + q)*NSEQ + s0 + sw + st*16 + colm[reg];
            unsigned long long bb = (unsigned long long)__double_as_longlong(sc);
            unsigned long long u = (bb & 0x8000000000000000ULL) ? ~bb : (bb | 0x8000000000000000ULL);
            K32[oidx] = (unsigned int)(u >> 32);
            L32[oidx] = (unsigned int)u;
        }
    }
}

// ------------------------------------------------------------------
// Block-per-query top-128: hi32 radix select w/ early exit.
// v2: uniform-row fast paths, per-wave histograms, ballot-coalesced
// LDS atomics (kills the -0.0 degenerate-row serialization).
// ------------------------------------------------------------------
__global__ __launch_bounds__(256) void k_topk(const unsigned int* __restrict__ K32,
                                              const unsigned int* __restrict__ L32,
                                              int* __restrict__ IDX, int qstart) {
    __shared__ unsigned int key[NSEQ + NSEQ/16];   // 17408 B
    __shared__ unsigned int candMask[NSEQ/32];     // 512 B
    __shared__ unsigned int hist[4][256];          // 4 KB (per-wave)
    __shared__ unsigned int s_ph, s_need, s_flag, s_cnt, s_uni;
    __shared__ unsigned int wsum[4];
    const int t = threadIdx.x, lane = t & 63, wid = t >> 6;
    const int q = blockIdx.x;
    const unsigned int* krow = K32 + (size_t)q * NSEQ;
    const unsigned int* lrow = L32 + (size_t)q * NSEQ;
    int* orow = IDX + (size_t)(qstart + q) * TOPK;

    auto pad = [](int i) { return i + (i >> 4); };

    // wave-private histogram add with uniform-digit coalescing
    auto hadd = [&](bool act, unsigned int d) {
        unsigned long long bal = __ballot(act);
        if (!bal) return;
        int src = __ffsll((unsigned long long)bal) - 1;
        unsigned int d0 = __shfl(d, src, 64);
        bool uni = (__ballot(act && d == d0) == bal);
        if (uni) {
            if (lane == src) hist[wid][d0] += (unsigned int)__popcll(bal);
        } else if (act) {
            atomicAdd(&hist[wid][d], 1u);
        }
    };

    auto decide = [&]() {
        if (wid == 0) {
            unsigned int c[4];
            #pragma unroll
            for (int k = 0; k < 4; k++)
                c[k] = hist[0][lane*4+k] + hist[1][lane*4+k] + hist[2][lane*4+k] + hist[3][lane*4+k];
            unsigned int run = c[0] + c[1] + c[2] + c[3];
            for (int d = 1; d < 64; d <<= 1) {
                unsigned int v = __shfl_down(run, d, 64);
                if (lane + d < 64) run += v;
            }
            unsigned int need = s_need;
            unsigned int Sb[5];
            Sb[0] = run; Sb[1] = run - c[0]; Sb[2] = Sb[1] - c[1];
            Sb[3] = Sb[2] - c[2]; Sb[4] = Sb[3] - c[3];
            for (int j = 0; j < 4; j++) {
                if (Sb[j] >= need && Sb[j+1] < need) {
                    unsigned int newneed = need - Sb[j+1];
                    s_ph   = (s_ph << 8) | (unsigned int)(lane*4 + j);
                    s_need = newneed;
                    if (newneed == Sb[j] - Sb[j+1]) s_flag = 1;
                }
            }
        }
        __syncthreads();
    };

    // ---- load K32 + uniformity check ----
    unsigned int k0 = krow[0];
    bool myeq = true;
    for (int j = 0; j < 16; j++) {
        int i = t + 256*j;
        unsigned int h = krow[i];
        key[pad(i)] = h;
        myeq &= (h == k0);
    }
    if (lane == 0) wsum[wid] = (__ballot(myeq) == ~0ULL) ? 1u : 0u;
    if (t == 0) { s_ph = 0; s_need = TOPK; s_flag = 0; s_cnt = 0; }
    __syncthreads();
    if (t == 0) s_uni = wsum[0] & wsum[1] & wsum[2] & wsum[3];
    __syncthreads();

    if (s_uni) {
        // all hi32 equal -> candidates = everything; check lo32 uniformity
        unsigned int l0 = lrow[0];
        bool me2 = true;
        for (int j = 0; j < 16; j++) {
            int i = t + 256*j;
            unsigned int h = lrow[i];
            key[pad(i)] = h;
            me2 &= (h == l0);
        }
        if (lane == 0) wsum[wid] = (__ballot(me2) == ~0ULL) ? 1u : 0u;
        __syncthreads();
        if (t == 0) s_uni = wsum[0] & wsum[1] & wsum[2] & wsum[3];
        __syncthreads();
        if (s_uni) {
            // everything ties -> lowest 128 indices
            if (t < TOPK) orow[t] = t;
            return;
        }
        if (t < 128) candMask[t] = 0xFFFFFFFFu;
        __syncthreads();
        // fall through to stage B with s_ph=0, s_need=TOPK
    } else {
        // ---- stage A: radix select on hi32 ----
        int plen = 0;
        for (int p = 0; p < 4; p++) {
            #pragma unroll
            for (int a = 0; a < 4; a++) hist[a][t] = 0;
            __syncthreads();
            unsigned int ph = s_ph;
            const int sh = 24 - 8*p;
            for (int j = 0; j < 16; j++) {
                int i = t*16 + j;
                unsigned int h = key[pad(i)];
                bool act = (p == 0) || ((h >> (sh + 8)) == ph);
                hadd(act, (h >> sh) & 255u);
            }
            __syncthreads();
            decide();
            plen += 8;
            if (s_flag) break;
        }

        if (s_flag) {
            unsigned int P = s_ph;
            int shr = 32 - plen;
            for (int j = 0; j < 16; j++) {
                int i = t*16 + j;
                if ((key[pad(i)] >> shr) >= P)
                    orow[atomicAdd(&s_cnt, 1u)] = i;
            }
            return;
        }

        // hi32 resolved: collect strict-greater, mark ties, swap in lo32
        unsigned int Hstar = s_ph;
        if (t < 128) candMask[t] = 0;
        __syncthreads();
        if (t == 0) s_ph = 0;
        for (int j = 0; j < 16; j++) {
            int i = t + 256*j;
            unsigned int h = key[pad(i)];
            if (h > Hstar) {
                orow[atomicAdd(&s_cnt, 1u)] = i;
            } else if (h == Hstar) {
                atomicOr(&candMask[i >> 5], 1u << (i & 31));
                key[pad(i)] = lrow[i];
            }
        }
        __syncthreads();
    }

    // ---- stage B: radix select on lo32 among candidates ----
    int plenB = 0;
    for (int p = 0; p < 4; p++) {
        #pragma unroll
        for (int a = 0; a < 4; a++) hist[a][t] = 0;
        __syncthreads();
        unsigned int ph = s_ph;
        const int sh = 24 - 8*p;
        for (int j = 0; j < 16; j++) {
            int i = t*16 + j;
            bool c = (candMask[i >> 5] >> (i & 31)) & 1u;
            unsigned int h = key[pad(i)];
            bool act = c && ((p == 0) || ((h >> (sh + 8)) == ph));
            hadd(act, (h >> sh) & 255u);
        }
        __syncthreads();
        decide();
        plenB += 8;
        if (s_flag) break;
    }

    if (s_flag) {
        unsigned int P = s_ph;
        int shr = 32 - plenB;
        for (int j = 0; j < 16; j++) {
            int i = t*16 + j;
            if ((candMask[i >> 5] >> (i & 31)) & 1u) {
                if ((key[pad(i)] >> shr) >= P)
                    orow[atomicAdd(&s_cnt, 1u)] = i;
            }
        }
        return;
    }

    // full 64-bit tie: strict-greater, then equals ascending by index
    unsigned int Lstar = s_ph;
    unsigned int r = s_need;
    unsigned int cnt = 0;
    for (int j = 0; j < 16; j++) {
        int i = t*16 + j;
        if ((candMask[i >> 5] >> (i & 31)) & 1u) {
            unsigned int h = key[pad(i)];
            if (h > Lstar) {
                orow[atomicAdd(&s_cnt, 1u)] = i;
            } else if (h == Lstar) cnt++;
        }
    }
    unsigned int inc = cnt;
    for (int d = 1; d < 64; d <<= 1) {
        unsigned int v = __shfl_up(inc, d, 64);
        if (lane >= d) inc += v;
    }
    if (lane == 63) wsum[wid] = inc;
    __syncthreads();
    unsigned int woff = 0;
    for (int w2 = 0; w2 < wid; w2++) woff += wsum[w2];
    unsigned int rk = woff + inc - cnt;
    unsigned int tbase = TOPK - r;
    for (int j = 0; j < 16; j++) {
        int i = t*16 + j;
        if ((candMask[i >> 5] >> (i & 31)) & 1u) {
            if (key[pad(i)] == Lstar) {
                if (rk < r) orow[tbase + rk] = i;
                rk++;
            }
        }
    }
}

// ------------------------------------------------------------------
// Attention stage 1: logits + softmax -> probs (global)
// ------------------------------------------------------------------
#define KVP 52
__global__ __launch_bounds__(256) void k_attn_qk(const float* __restrict__ Y,
                                                 const int* __restrict__ IDX,
                                                 float* __restrict__ Pr) {
    __shared__ float Ks[TOPK][KVP];
    __shared__ float qsh[NH*DKQ];
    __shared__ int   idxs[TOPK];
    const int g = blockIdx.x;
    const int b = g / NSEQ;
    const int t = threadIdx.x;

    if (t < TOPK) idxs[t] = IDX[(size_t)g*TOPK + t];
    for (int i = t; i < NH*DKQ; i += 256) qsh[i] = Y[(size_t)g*QKV_COLS + C_Q + i];
    __syncthreads();
    #pragma unroll
    for (int i = 0; i < 6; i++) {
        int e = t + 256*i;
        int j = e / 12, p = e % 12;
        const float* src = Y + (size_t)(b*NSEQ + idxs[j])*QKV_COLS + C_K;
        *(float4*)&Ks[j][p*4] = *(const float4*)(src + p*4);
    }
    __syncthreads();

    const int h  = t >> 5;
    const int j0 = t & 31;
    float lo[4] = {0.f, 0.f, 0.f, 0.f};
    #pragma unroll
    for (int c = 0; c < 12; c++) {
        float4 qv = *(const float4*)&qsh[h*DKQ + c*4];
        #pragma unroll
        for (int i = 0; i < 4; i++) {
            float4 kv = *(const float4*)&Ks[j0 + 32*i][c*4];
            lo[i] += qv.x*kv.x + qv.y*kv.y + qv.z*kv.z + qv.w*kv.w;
        }
    }
    #pragma unroll
    for (int i = 0; i < 4; i++) lo[i] *= ATT_SCALE;
    float m = fmaxf(fmaxf(lo[0], lo[1]), fmaxf(lo[2], lo[3]));
    for (int d = 16; d >= 1; d >>= 1) m = fmaxf(m, __shfl_xor(m, d, 64));
    float e0[4], sum = 0.f;
    #pragma unroll
    for (int i = 0; i < 4; i++) { e0[i] = __expf(lo[i] - m); sum += e0[i]; }
    for (int d = 16; d >= 1; d >>= 1) sum += __shfl_xor(sum, d, 64);
    float inv = 1.0f / sum;
    #pragma unroll
    for (int i = 0; i < 4; i++)
        Pr[(size_t)g*(NH*TOPK) + h*TOPK + j0 + 32*i] = e0[i] * inv;
}

// ------------------------------------------------------------------
// Attention stage 2: PV -> ctx (bf16 hi/lo split for out-proj GEMM)
// ------------------------------------------------------------------
__global__ __launch_bounds__(256) void k_attn_pv(const float* __restrict__ Y,
                                                 const int* __restrict__ IDX,
                                                 const float* __restrict__ Pr,
                                                 unsigned short* __restrict__ ctx_hi,
                                                 unsigned short* __restrict__ ctx_lo) {
    __shared__ float Vs[TOPK][KVP];
    __shared__ float prs[NH*TOPK];
    __shared__ int   idxs[TOPK];
    const int g = blockIdx.x;
    const int b = g / NSEQ;
    const int t = threadIdx.x;

    if (t < TOPK) idxs[t] = IDX[(size_t)g*TOPK + t];
    *(float4*)&prs[t*4] = *(const float4*)(Pr + (size_t)g*(NH*TOPK) + t*4);
    __syncthreads();
    #pragma unroll
    for (int i = 0; i < 6; i++) {
        int e = t + 256*i;
        int j = e / 12, p = e % 12;
        const float* src = Y + (size_t)(b*NSEQ + idxs[j])*QKV_COLS + C_V;
        *(float4*)&Vs[j][p*4] = *(const float4*)(src + p*4);
    }
    __syncthreads();

    for (int o = t; o < NH*DV; o += 256) {
        int hh = o / DV, dd = o % DV;
        float acc = 0.f;
        #pragma unroll
        for (int jc = 0; jc < 32; jc++) {
            float4 pv = *(const float4*)&prs[hh*TOPK + jc*4];
            acc += pv.x*Vs[jc*4+0][dd] + pv.y*Vs[jc*4+1][dd]
                 + pv.z*Vs[jc*4+2][dd] + pv.w*Vs[jc*4+3][dd];
        }
        unsigned short h, l;
        bsplit(acc, h, l);
        ctx_hi[(size_t)g*(NH*DV) + o] = h;
        ctx_lo[(size_t)g*(NH*DV) + o] = l;
    }
}

// ------------------------------------------------------------------
extern "C" void kernel_launch(void* const* d_in, const int* in_sizes, int n_in,
                              void* d_out, int out_size, void* d_ws, size_t ws_size,
                              hipStream_t stream) {
    const float* x      = (const float*)d_in[0];
    const float* wq_idx = (const float*)d_in[1];
    const float* wk_idx = (const float*)d_in[2];
    const float* ww_idx = (const float*)d_in[3];
    const float* wq     = (const float*)d_in[4];
    const float* wk     = (const float*)d_in[5];
    const float* wv     = (const float*)d_in[6];
    const float* wo     = (const float*)d_in[7];
    float* out = (float*)d_out;
    char*  ws  = (char*)d_ws;

    size_t off = 0;
    auto carve = [&](size_t bytes) { size_t o = off; off = (off + bytes + 255) & ~(size_t)255; return o; };
    size_t oWqh = carve((size_t)QKV_COLS*DMODEL*2);
    size_t oWql = carve((size_t)QKV_COLS*DMODEL*2);
    size_t oWoh = carve((size_t)DMODEL*DMODEL*2);
    size_t oWol = carve((size_t)DMODEL*DMODEL*2);
    size_t oWi  = carve((size_t)DMODEL*IDX_COLS*4);
    size_t oXh  = carve((size_t)NQ*DMODEL*2);
    size_t oXl  = carve((size_t)NQ*DMODEL*2);
    size_t oY   = carve((size_t)NQ*QKV_COLS*4);
    size_t oP   = carve((size_t)NQ*IDX_COLS*8);
    size_t oIdx = carve((size_t)NQ*TOPK*4);
    size_t oPr  = carve((size_t)NQ*NH*TOPK*4);
    size_t oCh  = carve((size_t)NQ*NH*DV*2);
    size_t oCl  = carve((size_t)NQ*NH*DV*2);
    size_t oKL  = off;

    // chunk region: K32 (4 B) + L32 (4 B) per score
    int QC = NSEQ;
    while (QC > 32 && oKL + (size_t)QC*NSEQ*8 > ws_size) QC >>= 1;

    unsigned short* WqT_hi = (unsigned short*)(ws + oWqh);
    unsigned short* WqT_lo = (unsigned short*)(ws + oWql);
    unsigned short* WoT_hi = (unsigned short*)(ws + oWoh);
    unsigned short* WoT_lo = (unsigned short*)(ws + oWol);
    float*  Wi_cat = (float*)(ws + oWi);
    unsigned short* xhi = (unsigned short*)(ws + oXh);
    unsigned short* xlo = (unsigned short*)(ws + oXl);
    float*  Y      = (float*)(ws + oY);
    double* P      = (double*)(ws + oP);
    int*    IDX    = (int*)(ws + oIdx);
    float*  Pr     = (float*)(ws + oPr);
    unsigned short* ctx_hi = (unsigned short*)(ws + oCh);
    unsigned short* ctx_lo = (unsigned short*)(ws + oCl);
    unsigned int* K32 = (unsigned int*)(ws + oKL);
    unsigned int* L32 = (unsigned int*)(ws + oKL + (size_t)QC*NSEQ*4);

    int ncat = QKV_COLS*DMODEL + DMODEL*DMODEL + DMODEL*IDX_COLS;
    k_split<<<(NQ*DMODEL + 255)/256, 256, 0, stream>>>(x, xhi, xlo);
    k_concat<<<(ncat + 255)/256, 256, 0, stream>>>(wq_idx, wk_idx, ww_idx, wq, wk, wv, wo,
                                                   WqT_hi, WqT_lo, WoT_hi, WoT_lo, Wi_cat);
    k_gemm_mfma<<<dim3((QKV_COLS + 63)/64, NQ/128), 256, 0, stream>>>(xhi, xlo, WqT_hi, WqT_lo, Y, QKV_COLS, QKV_COLS);
    k_proj64<<<NQ/32, 256, 0, stream>>>(x, Wi_cat, P);
    for (int qs = 0; qs < NQ; qs += QC) {
        k_score_mfma<<<dim3(NSEQ/128, QC/32), 256, 0, stream>>>(P, K32, L32, qs);
        k_topk<<<QC, 256, 0, stream>>>(K32, L32, IDX, qs);
    }
    k_attn_qk<<<NQ, 256, 0, stream>>>(Y, IDX, Pr);
    k_attn_pv<<<NQ, 256, 0, stream>>>(Y, IDX, Pr, ctx_hi, ctx_lo);
    k_gemm_mfma<<<dim3(DMODEL/64, NQ/128), 256, 0, stream>>>(ctx_hi, ctx_lo, WoT_hi, WoT_lo, out, DMODEL, DMODEL);
}